// Round 3
// baseline (786.857 us; speedup 1.0000x reference)
//
#include <hip/hip_runtime.h>
#include <hip/hip_bf16.h>
#include <cstdint>
#include <cstddef>

typedef unsigned short u16;
typedef unsigned int   u32;
typedef unsigned char  u8;

#define NCLS 41

typedef short s16x8 __attribute__((ext_vector_type(8)));
typedef float f32x4 __attribute__((ext_vector_type(4)));

__device__ __forceinline__ u16 f2bf(float f) {          // RNE float->bf16
  u32 u = __float_as_uint(f);
  u += 0x7fffu + ((u >> 16) & 1u);
  return (u16)(u >> 16);
}

// ---- async global->LDS (16B/lane, wave-uniform LDS base) ------------------
#if __has_builtin(__builtin_amdgcn_global_load_lds)
#define HAVE_GLL 1
typedef const __attribute__((address_space(1))) u32* gas1p;
typedef __attribute__((address_space(3))) u32* las3p;
__device__ __forceinline__ void gll16(const void* g, void* l) {
  __builtin_amdgcn_global_load_lds((gas1p)g, (las3p)l, 16, 0, 0);
}
#else
#define HAVE_GLL 0
#endif

// ===========================================================================
// K_w: w_fuse [128oc][256ic][3][3] f32  ->  Wt [9tap][128oc][256ic] bf16
// ===========================================================================
__global__ void k_wprep(const float* __restrict__ wf, u16* __restrict__ Wt) {
  const int e = blockIdx.x * 256 + threadIdx.x;
  if (e >= 9 * 128 * 256) return;
  const int tap = e / (128 * 256);
  const int oc  = (e / 256) % 128;
  const int ic  = e % 256;
  Wt[e] = f2bf(wf[((size_t)oc * 256 + ic) * 9 + tap]);
}

// ===========================================================================
// K2: labels_ds (::4,::4) -> u8 [4][224][224]; histogram -> counts[4*41]
// ===========================================================================
__global__ void k_labels(const int* __restrict__ label, u8* __restrict__ labs,
                         int* __restrict__ counts) {
  const int i = blockIdx.x % 224, b = blockIdx.x / 224;
  __shared__ int hist[NCLS];
  const int t = threadIdx.x;
  if (t < NCLS) hist[t] = 0;
  __syncthreads();
  if (t < 224) {
    const int v = label[((size_t)b * 896 + 4 * i) * 896 + 4 * t];
    labs[((size_t)b * 224 + i) * 224 + t] = (u8)v;
    atomicAdd(&hist[v], 1);
  }
  __syncthreads();
  if (t < NCLS) atomicAdd(&counts[b * NCLS + t], hist[t]);
}

// ===========================================================================
// K1: build X = padded bf16, SLICE-MAJOR layout:
//     X[b][yp][s][px][32ch], s=0..7: s<4 -> a=r+d (ch 32s..), s>=4 -> m=r*sig(d).
//     Register transpose: thread = pixel, serial channel walk.  At fixed c,
//     lanes read consecutive floats (coalesced); thread packs 16 ch into 8
//     u32 regs and stores 2x uint4 (lanes -> 64B-strided contiguous runs).
//     NO staging LDS, NO barriers in the stream loop -> deep MLP.
//     Block = (b, yp, g): g = channel half (64 ch).  d-segsum fused as LDS
//     atomics acc[lab*65+c] (10.7 KB), flushed once.
// ===========================================================================
__global__ __launch_bounds__(256) void k_prep(const float* __restrict__ r,
                                              const float* __restrict__ d,
                                              const u8* __restrict__ labs,
                                              u16* __restrict__ X,
                                              float* __restrict__ sums_d) {
  const int t  = threadIdx.x;
  const int g  = blockIdx.x & 1;
  const int yp = (blockIdx.x >> 1) % 226;
  const int b  = blockIdx.x / 452;

  if (yp == 0 || yp == 225) {                       // y-halo rows: zero 4 slices
    for (int e = t; e < 4 * 226 * 4; e += 256) {    // uint4 units
      const int sl = e / 904, rm = e % 904;
      const int s = (sl & 1) + g * 2 + (sl >> 1) * 4;
      uint4* p = (uint4*)(X + (((size_t)(b * 226 + yp) * 8 + s) * 226) * 32) + rm;
      *p = uint4{0u, 0u, 0u, 0u};
    }
    return;
  }
  const int y = yp - 1;

  __shared__ float acc[NCLS * 65];                  // seg-sum of d (64 ch + pad)
  for (int e = t; e < NCLS * 65; e += 256) acc[e] = 0.f;
  __syncthreads();

  if (t < 224) {
    const int x = t;
    const int lab = (int)labs[((size_t)b * 224 + y) * 224 + x];
    const float* rb = r + ((size_t)b * 128 + g * 64) * 50176 + y * 224 + x;
    const float* db = d + ((size_t)b * 128 + g * 64) * 50176 + y * 224 + x;
    for (int c0 = 0; c0 < 64; c0 += 16) {
      float rv[16], dv[16];
#pragma unroll
      for (int j = 0; j < 16; ++j) {
        rv[j] = rb[(size_t)(c0 + j) * 50176];
        dv[j] = db[(size_t)(c0 + j) * 50176];
      }
#pragma unroll
      for (int j = 0; j < 16; ++j)
        atomicAdd(&acc[lab * 65 + c0 + j], dv[j]);
      u32 pa[8], pm[8];
#pragma unroll
      for (int j = 0; j < 8; ++j) {
        const float r0 = rv[2 * j], r1 = rv[2 * j + 1];
        const float d0 = dv[2 * j], d1 = dv[2 * j + 1];
        pa[j] = (u32)f2bf(r0 + d0) | ((u32)f2bf(r1 + d1) << 16);
        pm[j] = (u32)f2bf(r0 / (1.f + __expf(-d0)))
              | ((u32)f2bf(r1 / (1.f + __expf(-d1))) << 16);
      }
      const int s  = g * 2 + (c0 >> 5);             // a-slice; m-slice = s+4
      const int qo = (c0 & 31) >> 1;                // u32 offset within slice-px
      u32* Xa = (u32*)(X + ((((size_t)(b * 226 + yp) * 8 + s)     * 226) + (x + 1)) * 32) + qo;
      u32* Xm = (u32*)(X + ((((size_t)(b * 226 + yp) * 8 + s + 4) * 226) + (x + 1)) * 32) + qo;
      *(uint4*)(Xa)     = uint4{pa[0], pa[1], pa[2], pa[3]};
      *(uint4*)(Xa + 4) = uint4{pa[4], pa[5], pa[6], pa[7]};
      *(uint4*)(Xm)     = uint4{pm[0], pm[1], pm[2], pm[3]};
      *(uint4*)(Xm + 4) = uint4{pm[4], pm[5], pm[6], pm[7]};
    }
  } else {                                          // t in [224,256): x-halos
    const int idx = t - 224;                        // 4 slices x 2 px x 4 chunks
    const int chunk = idx & 3, pxsel = (idx >> 2) & 1, sl = idx >> 3;
    const int s = (sl & 1) + g * 2 + (sl >> 1) * 4;
    const int px = pxsel * 225;
    uint4* p = (uint4*)(X + ((((size_t)(b * 226 + yp) * 8 + s) * 226) + px) * 32) + chunk;
    *p = uint4{0u, 0u, 0u, 0u};
  }
  __syncthreads();                                  // acc complete
  for (int e = t; e < NCLS * 64; e += 256)
    atomicAdd(&sums_d[(size_t)b * NCLS * 128 + (e >> 6) * 128 + g * 64 + (e & 63)],
              acc[(e >> 6) * 65 + (e & 63)]);
}

// ===========================================================================
// K4: conv3x3 as implicit GEMM, bf16 MFMA 16x16x32.  2-PHASE DOUBLE BUFFER
//     (T3-lite): per K-step, issue next step's global_load_lds into buf^1
//     BEFORE ds_read+MFMA of buf, then ONE barrier (its vmcnt drain lands
//     after the compute has covered the load latency).  72 flat K-steps
//     (tap*8+s).  LDS 32 KB.  XCD-band swizzle on L%8.
// ===========================================================================
__global__ __launch_bounds__(256) void k_conv(const u16* __restrict__ X,
                                              const u16* __restrict__ Wt,
                                              u16* __restrict__ fuse) {
  __shared__ u16 Alds[2][128 * 32];
  __shared__ u16 Blds[2][128 * 32];
  const int t = threadIdx.x;
  const int w = t >> 6, l = t & 63;
  const int lrow = l & 15, lq = l >> 4;
  const int wm = (w & 1) * 64, wn = (w >> 1) * 64;

  const int L   = blockIdx.x;        // 1792 blocks
  const int xcd = L & 7;             // heuristic: linear id % 8 = XCD
  const int i   = L >> 3;            // 0..223
  const int b   = i / 56;
  const int rem = i % 56;            // 28 y x 2 xtiles
  const int y   = xcd * 28 + (rem >> 1);
  const int x0  = (rem & 1) * 128;

  f32x4 acc[4][4] = {};

  const int posA = t >> 2;          // staging: lane covers (pos, 8-ch chunk)
  const int koff = (t & 3) * 8;
  const size_t browb = (size_t)(b * 226 + y) * 8;   // slice-major row base, dy=0
  const int ldsoff = (w * 64) * 16;                 // wave-uniform LDS offset

  auto stage = [&](int step, int buf) {
    const int tap = step >> 3, s = step & 7;
    const int dy = tap / 3, dx = tap % 3;
    const u16* ga0 = X + ((browb + dy * 8 + s) * 226 + (x0 + dx) + posA) * 32 + koff;
    const u16* gb0 = Wt + (size_t)tap * (128 * 256) + (size_t)posA * 256 + s * 32 + koff;
    char* la = (char*)Alds[buf] + ldsoff;
    char* lb = (char*)Blds[buf] + ldsoff;
#if HAVE_GLL
    gll16(ga0, la);
    gll16(gb0, lb);
    gll16(ga0 + 64 * 32,  la + 256 * 16);
    gll16(gb0 + 64 * 256, lb + 256 * 16);
#else
    *(uint4*)((char*)Alds[buf] + (size_t)t * 16)         = *(const uint4*)ga0;
    *(uint4*)((char*)Blds[buf] + (size_t)t * 16)         = *(const uint4*)gb0;
    *(uint4*)((char*)Alds[buf] + (size_t)(256 + t) * 16) = *(const uint4*)(ga0 + 64 * 32);
    *(uint4*)((char*)Blds[buf] + (size_t)(256 + t) * 16) = *(const uint4*)(gb0 + 64 * 256);
#endif
  };

  stage(0, 0);
  __syncthreads();                   // buf0 ready (syncthreads drains vmcnt)
  int cur = 0;
  for (int step = 0; step < 72; ++step) {
    if (step < 71) stage(step + 1, cur ^ 1);   // async prefetch into free buffer
    const char* A = (const char*)Alds[cur];
    const char* B = (const char*)Blds[cur];
    s16x8 af[4], bfr[4];
#pragma unroll
    for (int mi = 0; mi < 4; ++mi)
      af[mi] = *(const s16x8*)(A + (wm + mi * 16 + lrow) * 64 + lq * 16);
#pragma unroll
    for (int ni = 0; ni < 4; ++ni)
      bfr[ni] = *(const s16x8*)(B + (wn + ni * 16 + lrow) * 64 + lq * 16);
#pragma unroll
    for (int mi = 0; mi < 4; ++mi)
#pragma unroll
      for (int ni = 0; ni < 4; ++ni)
        acc[mi][ni] = __builtin_amdgcn_mfma_f32_16x16x32_bf16(af[mi], bfr[ni], acc[mi][ni], 0, 0, 0);
    __syncthreads();                 // prefetch landed + all waves done reading cur
    cur ^= 1;
  }
  // epilogue: D row = pos (C/D layout row = lq*4+reg), col = oc (l&15)
#pragma unroll
  for (int mi = 0; mi < 4; ++mi) {
#pragma unroll
    for (int rr = 0; rr < 4; ++rr) {
      const int pos = wm + mi * 16 + lq * 4 + rr;
      const int x = x0 + pos;
      if (x < 224) {
        u16* dst = fuse + ((size_t)(b * 224 + y) * 224 + x) * 128;
#pragma unroll
        for (int ni = 0; ni < 4; ++ni) {
          const int oc = wn + ni * 16 + lrow;
          dst[oc] = f2bf(acc[mi][ni][rr]);
        }
      }
    }
  }
}

// ===========================================================================
// K5: segment-sum of fuse (NHWC bf16) -> global atomics into sums_f.
//     Block = (b, y): one row, 224 px x 64 u32.  Lanes walk channels of one
//     pixel -> all lanes share the label, distinct channels (no same-addr
//     serialization).
// ===========================================================================
__global__ __launch_bounds__(256) void k_segf(const u16* __restrict__ fuse,
                                              const u8* __restrict__ labs,
                                              float* __restrict__ sums_f) {
  const int y = blockIdx.x % 224, b = blockIdx.x / 224;
  __shared__ float acc[NCLS * 129];
  __shared__ u8 ll[224];
  const int t = threadIdx.x;
  for (int e = t; e < NCLS * 129; e += 256) acc[e] = 0.f;
  if (t < 224) ll[t] = labs[((size_t)b * 224 + y) * 224 + t];
  __syncthreads();
  const u32* fb = (const u32*)(fuse + ((size_t)b * 224 + y) * 224 * 128);
  for (int e = t; e < 224 * 64; e += 256) {
    const int c2 = e % 64, px = e / 64;
    const u32 v = fb[(size_t)px * 64 + c2];
    const int lab = ll[px];
    atomicAdd(&acc[lab * 129 + 2 * c2],     __uint_as_float(v << 16));
    atomicAdd(&acc[lab * 129 + 2 * c2 + 1], __uint_as_float(v & 0xffff0000u));
  }
  __syncthreads();
  for (int e = t; e < NCLS * 128; e += 256)
    atomicAdd(&sums_f[b * NCLS * 128 + e], acc[(e / 128) * 129 + (e % 128)]);
}

// ===========================================================================
// K6: gates.  One block per batch, reads tiny sums[b][41][128].
// ===========================================================================
__global__ __launch_bounds__(256) void k_gates(const float* __restrict__ sums,
                                               const int* __restrict__ counts,
                                               const float* __restrict__ w1,
                                               const float* __restrict__ w2,
                                               float* __restrict__ gates) {
  const int b = blockIdx.x;
  __shared__ float att[128];
  __shared__ float hid[8];
  const int t = threadIdx.x;
  if (t < 128) {
    float s1 = 0.f, s2 = 0.f;
    for (int lb = 0; lb < NCLS; ++lb) {
      const float cnt = (float)counts[b * NCLS + lb];
      const float m = sums[(size_t)b * NCLS * 128 + lb * 128 + t] / fmaxf(cnt, 1.f);
      s1 += m; s2 += m * m;
    }
    att[t] = s1 / fmaxf(sqrtf(s2), 1e-12f);
  }
  __syncthreads();
  if (t < 8) {
    float h = 0.f;
    for (int c = 0; c < 128; ++c) h += att[c] * w1[t * 128 + c];
    hid[t] = fmaxf(h, 0.f);
  }
  __syncthreads();
  if (t < 128) {
    float o = 0.f;
    for (int j = 0; j < 8; ++j) o += hid[j] * w2[t * 8 + j];
    gates[b * 128 + t] = 1.f / (1.f + expf(-o));
  }
}

// ===========================================================================
// K7: out(NCHW f32) = fuse(NHWC bf16)*gate_f + d(NCHW)*gate_d
//     Block = (b,y); LDS transpose of fuse row back to channel-major.
// ===========================================================================
__global__ __launch_bounds__(256) void k_out(const u16* __restrict__ fuse,
                                             const float* __restrict__ d,
                                             const float* __restrict__ gates,
                                             float* __restrict__ out) {
  const int y = blockIdx.x % 224, b = blockIdx.x / 224;
  __shared__ float flds[224 * 33];
  __shared__ float gf[128], gd[128];
  const int t = threadIdx.x;
  if (t < 128) gd[t] = gates[b * 128 + t];
  else         gf[t - 128] = gates[512 + b * 128 + (t - 128)];
  const u32* frow = (const u32*)fuse + ((size_t)b * 224 + y) * 224 * 64;
  const float* db = d + (size_t)b * 128 * 50176 + y * 224;
  float* ob = out + (size_t)b * 128 * 50176 + y * 224;
  for (int c0 = 0; c0 < 128; c0 += 32) {
    __syncthreads();
    for (int e = t; e < 224 * 16; e += 256) {
      const int px = e / 16, q = e % 16;
      const u32 v = frow[(size_t)px * 64 + (c0 >> 1) + q];
      flds[px * 33 + 2 * q]     = __uint_as_float(v << 16);
      flds[px * 33 + 2 * q + 1] = __uint_as_float(v & 0xffff0000u);
    }
    __syncthreads();
    for (int e = t; e < 32 * 224; e += 256) {
      const int cc = e / 224, x = e % 224, c = c0 + cc;
      ob[(size_t)c * 50176 + x] = flds[x * 33 + cc] * gf[c] + db[(size_t)c * 50176 + x] * gd[c];
    }
  }
}

// ===========================================================================
extern "C" void kernel_launch(void* const* d_in, const int* in_sizes, int n_in,
                              void* d_out, int out_size, void* d_ws, size_t ws_size,
                              hipStream_t stream) {
  const float* r     = (const float*)d_in[0];
  const float* d     = (const float*)d_in[1];
  const int*   label = (const int*)d_in[2];
  const float* wf    = (const float*)d_in[3];
  const float* w1d   = (const float*)d_in[4];
  const float* w2d   = (const float*)d_in[5];
  const float* w1f   = (const float*)d_in[6];
  const float* w2f   = (const float*)d_in[7];
  float* out = (float*)d_out;

  char* ws = (char*)d_ws;
  size_t off = 0;
  auto carve = [&](size_t bytes) -> char* {
    char* p = ws + off;
    off = (off + bytes + 511) & ~(size_t)511;
    return p;
  };
  u16* X       = (u16*)carve((size_t)4 * 226 * 226 * 256 * 2 + 65536);  // slice-major + OOB pad
  u16* Wt      = (u16*)carve((size_t)9 * 128 * 256 * 2);
  u16* fuseb   = (u16*)carve((size_t)4 * 224 * 224 * 128 * 2);
  u8*  labs    = (u8*) carve((size_t)4 * 224 * 224);
  int* counts  = (int*)carve(4 * NCLS * sizeof(int));
  float* sumsd = (float*)carve((size_t)4 * NCLS * 128 * 4);
  float* sumsf = (float*)carve((size_t)4 * NCLS * 128 * 4);
  float* gates = (float*)carve(1024 * sizeof(float));

  hipMemsetAsync(counts, 0, 4 * NCLS * sizeof(int), stream);
  hipMemsetAsync(sumsd, 0, (size_t)4 * NCLS * 128 * 4, stream);
  hipMemsetAsync(sumsf, 0, (size_t)4 * NCLS * 128 * 4, stream);
  k_wprep <<<(9 * 128 * 256 + 255) / 256, 256, 0, stream>>>(wf, Wt);
  k_labels<<<4 * 224, 256, 0, stream>>>(label, labs, counts);
  k_prep  <<<4 * 226 * 2, 256, 0, stream>>>(r, d, labs, X, sumsd);
  k_conv  <<<1792, 256, 0, stream>>>(X, Wt, fuseb);
  k_segf  <<<4 * 224, 256, 0, stream>>>(fuseb, labs, sumsf);
  k_gates <<<4, 256, 0, stream>>>(sumsd, counts, w1d, w2d, gates);        // gates[0..511]   = d-module
  k_gates <<<4, 256, 0, stream>>>(sumsf, counts, w1f, w2f, gates + 512);  // gates[512..1023]= fuse-module
  k_out   <<<4 * 224, 256, 0, stream>>>(fuseb, d, gates, out);
}

// Round 4
// 720.632 us; speedup vs baseline: 1.0919x; 1.0919x over previous
//
#include <hip/hip_runtime.h>
#include <hip/hip_bf16.h>
#include <cstdint>
#include <cstddef>

typedef unsigned short u16;
typedef unsigned int   u32;
typedef unsigned char  u8;

#define NCLS 41

typedef short s16x8 __attribute__((ext_vector_type(8)));
typedef float f32x4 __attribute__((ext_vector_type(4)));

__device__ __forceinline__ u16 f2bf(float f) {          // RNE float->bf16
  u32 u = __float_as_uint(f);
  u += 0x7fffu + ((u >> 16) & 1u);
  return (u16)(u >> 16);
}

// ---- async global->LDS (16B/lane, wave-uniform LDS base) ------------------
#if __has_builtin(__builtin_amdgcn_global_load_lds)
#define HAVE_GLL 1
typedef const __attribute__((address_space(1))) u32* gas1p;
typedef __attribute__((address_space(3))) u32* las3p;
__device__ __forceinline__ void gll16(const void* g, void* l) {
  __builtin_amdgcn_global_load_lds((gas1p)g, (las3p)l, 16, 0, 0);
}
#else
#define HAVE_GLL 0
#endif

// ===========================================================================
// K_w: w_fuse [128oc][256ic][3][3] f32  ->  Wt [9tap][128oc][256ic] bf16
// ===========================================================================
__global__ void k_wprep(const float* __restrict__ wf, u16* __restrict__ Wt) {
  const int e = blockIdx.x * 256 + threadIdx.x;
  if (e >= 9 * 128 * 256) return;
  const int tap = e / (128 * 256);
  const int oc  = (e / 256) % 128;
  const int ic  = e % 256;
  Wt[e] = f2bf(wf[((size_t)oc * 256 + ic) * 9 + tap]);
}

// ===========================================================================
// K2: labels_ds (::4,::4) -> u8 [4][224][224]; histogram -> counts[4*41]
// ===========================================================================
__global__ void k_labels(const int* __restrict__ label, u8* __restrict__ labs,
                         int* __restrict__ counts) {
  const int i = blockIdx.x % 224, b = blockIdx.x / 224;
  __shared__ int hist[NCLS];
  const int t = threadIdx.x;
  if (t < NCLS) hist[t] = 0;
  __syncthreads();
  if (t < 224) {
    const int v = label[((size_t)b * 896 + 4 * i) * 896 + 4 * t];
    labs[((size_t)b * 224 + i) * 224 + t] = (u8)v;
    atomicAdd(&hist[v], 1);
  }
  __syncthreads();
  if (t < NCLS) atomicAdd(&counts[b * NCLS + t], hist[t]);
}

// ===========================================================================
// K1: build X = padded bf16, SLICE-MAJOR layout:
//     X[b][yp][s][px][32ch], s=0..7: s<4 -> a=r+d (ch 32s..), s>=4 -> m=r*sig(d).
//     Register transpose: thread = pixel, serial channel walk.  At fixed c,
//     lanes read consecutive floats (coalesced); thread packs 16 ch into 8
//     u32 regs and stores 2x uint4 (lanes -> 64B-strided contiguous runs).
//     NO staging LDS, NO barriers in the stream loop -> deep MLP.
//     Block = (b, yp, g): g = channel half (64 ch).  d-segsum fused as LDS
//     atomics acc[lab*65+c] (10.7 KB), flushed once.
// ===========================================================================
__global__ __launch_bounds__(256) void k_prep(const float* __restrict__ r,
                                              const float* __restrict__ d,
                                              const u8* __restrict__ labs,
                                              u16* __restrict__ X,
                                              float* __restrict__ sums_d) {
  const int t  = threadIdx.x;
  const int g  = blockIdx.x & 1;
  const int yp = (blockIdx.x >> 1) % 226;
  const int b  = blockIdx.x / 452;

  if (yp == 0 || yp == 225) {                       // y-halo rows: zero 4 slices
    for (int e = t; e < 4 * 226 * 4; e += 256) {    // uint4 units
      const int sl = e / 904, rm = e % 904;
      const int s = (sl & 1) + g * 2 + (sl >> 1) * 4;
      uint4* p = (uint4*)(X + (((size_t)(b * 226 + yp) * 8 + s) * 226) * 32) + rm;
      *p = uint4{0u, 0u, 0u, 0u};
    }
    return;
  }
  const int y = yp - 1;

  __shared__ float acc[NCLS * 65];                  // seg-sum of d (64 ch + pad)
  for (int e = t; e < NCLS * 65; e += 256) acc[e] = 0.f;
  __syncthreads();

  if (t < 224) {
    const int x = t;
    const int lab = (int)labs[((size_t)b * 224 + y) * 224 + x];
    const float* rb = r + ((size_t)b * 128 + g * 64) * 50176 + y * 224 + x;
    const float* db = d + ((size_t)b * 128 + g * 64) * 50176 + y * 224 + x;
    for (int c0 = 0; c0 < 64; c0 += 16) {
      float rv[16], dv[16];
#pragma unroll
      for (int j = 0; j < 16; ++j) {
        rv[j] = rb[(size_t)(c0 + j) * 50176];
        dv[j] = db[(size_t)(c0 + j) * 50176];
      }
#pragma unroll
      for (int j = 0; j < 16; ++j)
        atomicAdd(&acc[lab * 65 + c0 + j], dv[j]);
      u32 pa[8], pm[8];
#pragma unroll
      for (int j = 0; j < 8; ++j) {
        const float r0 = rv[2 * j], r1 = rv[2 * j + 1];
        const float d0 = dv[2 * j], d1 = dv[2 * j + 1];
        pa[j] = (u32)f2bf(r0 + d0) | ((u32)f2bf(r1 + d1) << 16);
        pm[j] = (u32)f2bf(r0 / (1.f + __expf(-d0)))
              | ((u32)f2bf(r1 / (1.f + __expf(-d1))) << 16);
      }
      const int s  = g * 2 + (c0 >> 5);             // a-slice; m-slice = s+4
      const int qo = (c0 & 31) >> 1;                // u32 offset within slice-px
      u32* Xa = (u32*)(X + ((((size_t)(b * 226 + yp) * 8 + s)     * 226) + (x + 1)) * 32) + qo;
      u32* Xm = (u32*)(X + ((((size_t)(b * 226 + yp) * 8 + s + 4) * 226) + (x + 1)) * 32) + qo;
      *(uint4*)(Xa)     = uint4{pa[0], pa[1], pa[2], pa[3]};
      *(uint4*)(Xa + 4) = uint4{pa[4], pa[5], pa[6], pa[7]};
      *(uint4*)(Xm)     = uint4{pm[0], pm[1], pm[2], pm[3]};
      *(uint4*)(Xm + 4) = uint4{pm[4], pm[5], pm[6], pm[7]};
    }
  } else {                                          // t in [224,256): x-halos
    const int idx = t - 224;                        // 4 slices x 2 px x 4 chunks
    const int chunk = idx & 3, pxsel = (idx >> 2) & 1, sl = idx >> 3;
    const int s = (sl & 1) + g * 2 + (sl >> 1) * 4;
    const int px = pxsel * 225;
    uint4* p = (uint4*)(X + ((((size_t)(b * 226 + yp) * 8 + s) * 226) + px) * 32) + chunk;
    *p = uint4{0u, 0u, 0u, 0u};
  }
  __syncthreads();                                  // acc complete
  for (int e = t; e < NCLS * 64; e += 256)
    atomicAdd(&sums_d[(size_t)b * NCLS * 128 + (e >> 6) * 128 + g * 64 + (e & 63)],
              acc[(e >> 6) * 65 + (e & 63)]);
}

// ===========================================================================
// K4: conv3x3 as implicit GEMM, bf16 MFMA 16x16x32.  dx-SHARED phases:
//     phase = (dy, s): stage ONE 130-pos A panel (row y+dy, slice s) + the
//     3 dx B-panels, then compute all 3 dx from LDS (A read offset +dx*64B).
//     48 MFMA/wave between barriers (vs 16), 48 barriers (vs 144), A-fetch
//     cut 3x.  Single-buffered, 2 barriers/phase (R2 structure — the R3
//     explicit dbuf regressed: VALU addr-calc explosion, m99/m131 lesson).
//     XCD-band swizzle on L%8.
// ===========================================================================
__global__ __launch_bounds__(256) void k_conv(const u16* __restrict__ X,
                                              const u16* __restrict__ Wt,
                                              u16* __restrict__ fuse) {
  __shared__ u16 Alds[132 * 32];         // 130 pos used (+2 pad)
  __shared__ u16 Blds[3][128 * 32];
  const int t = threadIdx.x;
  const int w = t >> 6, l = t & 63;
  const int lrow = l & 15, lq = l >> 4;
  const int wm = (w & 1) * 64, wn = (w >> 1) * 64;

  const int L   = blockIdx.x;        // 1792 blocks
  const int xcd = L & 7;             // heuristic: linear id % 8 = XCD
  const int i   = L >> 3;            // 0..223
  const int b   = i / 56;
  const int rem = i % 56;            // 28 y x 2 xtiles
  const int y   = xcd * 28 + (rem >> 1);
  const int x0  = (rem & 1) * 128;

  f32x4 acc[4][4] = {};

  const int posA = t >> 2;          // staging: lane covers (pos/oc, 16B chunk)
  const int koff = (t & 3) * 8;     // u16 units
  const size_t browb = (size_t)(b * 226 + y) * 8;   // slice-major row base
  char* ldsA0 = (char*)Alds + (w * 64) * 16;        // wave-uniform LDS bases

  for (int dy = 0; dy < 3; ++dy) {
    for (int s = 0; s < 8; ++s) {
      const u16* Abase = X + ((browb + dy * 8 + s) * 226 + x0) * 32;
      // ---- stage A: 128 pos via 2 gll rounds + 2-pos tail (reg->LDS) ----
#if HAVE_GLL
      gll16(Abase + posA * 32 + koff,        ldsA0);
      gll16(Abase + (64 + posA) * 32 + koff, ldsA0 + 4096);
#else
      *(uint4*)((char*)Alds + t * 16)        = *(const uint4*)(Abase + posA * 32 + koff);
      *(uint4*)((char*)Alds + 4096 + t * 16) = *(const uint4*)(Abase + (64 + posA) * 32 + koff);
#endif
      if (t < 8)   // pos 128..129 (x0=128: in-bounds pad garbage, epilogue-masked)
        *(uint4*)((char*)Alds + 8192 + t * 16) = *(const uint4*)(Abase + 128 * 32 + t * 8);
      // ---- stage B: 3 taps (dy,dx) x 2 rounds --------------------------
#pragma unroll
      for (int dx = 0; dx < 3; ++dx) {
        const u16* Bbase = Wt + (size_t)(dy * 3 + dx) * (128 * 256) + s * 32;
        char* ldsB0 = (char*)Blds[dx] + (w * 64) * 16;
#if HAVE_GLL
        gll16(Bbase + posA * 256 + koff,        ldsB0);
        gll16(Bbase + (64 + posA) * 256 + koff, ldsB0 + 4096);
#else
        *(uint4*)((char*)Blds[dx] + t * 16)        = *(const uint4*)(Bbase + posA * 256 + koff);
        *(uint4*)((char*)Blds[dx] + 4096 + t * 16) = *(const uint4*)(Bbase + (64 + posA) * 256 + koff);
#endif
      }
      __syncthreads();
      // ---- compute: 3 dx from the shared A panel -----------------------
#pragma unroll
      for (int dx = 0; dx < 3; ++dx) {
        s16x8 af[4], bfr[4];
#pragma unroll
        for (int mi = 0; mi < 4; ++mi)
          af[mi] = *(const s16x8*)((const char*)Alds + (wm + mi * 16 + lrow + dx) * 64 + lq * 16);
#pragma unroll
        for (int ni = 0; ni < 4; ++ni)
          bfr[ni] = *(const s16x8*)((const char*)Blds[dx] + (wn + ni * 16 + lrow) * 64 + lq * 16);
#pragma unroll
        for (int mi = 0; mi < 4; ++mi)
#pragma unroll
          for (int ni = 0; ni < 4; ++ni)
            acc[mi][ni] = __builtin_amdgcn_mfma_f32_16x16x32_bf16(af[mi], bfr[ni], acc[mi][ni], 0, 0, 0);
      }
      __syncthreads();
    }
  }
  // epilogue: D row = pos (C/D layout row = lq*4+reg), col = oc (l&15)
#pragma unroll
  for (int mi = 0; mi < 4; ++mi) {
#pragma unroll
    for (int rr = 0; rr < 4; ++rr) {
      const int pos = wm + mi * 16 + lq * 4 + rr;
      const int x = x0 + pos;
      if (x < 224) {
        u16* dst = fuse + ((size_t)(b * 224 + y) * 224 + x) * 128;
#pragma unroll
        for (int ni = 0; ni < 4; ++ni) {
          const int oc = wn + ni * 16 + lrow;
          dst[oc] = f2bf(acc[mi][ni][rr]);
        }
      }
    }
  }
}

// ===========================================================================
// K5: segment-sum of fuse (NHWC bf16) -> global atomics into sums_f.
//     Block = (b, y): one row, 224 px x 64 u32.  Lanes walk channels of one
//     pixel -> all lanes share the label, distinct channels (no same-addr
//     serialization).
// ===========================================================================
__global__ __launch_bounds__(256) void k_segf(const u16* __restrict__ fuse,
                                              const u8* __restrict__ labs,
                                              float* __restrict__ sums_f) {
  const int y = blockIdx.x % 224, b = blockIdx.x / 224;
  __shared__ float acc[NCLS * 129];
  __shared__ u8 ll[224];
  const int t = threadIdx.x;
  for (int e = t; e < NCLS * 129; e += 256) acc[e] = 0.f;
  if (t < 224) ll[t] = labs[((size_t)b * 224 + y) * 224 + t];
  __syncthreads();
  const u32* fb = (const u32*)(fuse + ((size_t)b * 224 + y) * 224 * 128);
  for (int e = t; e < 224 * 64; e += 256) {
    const int c2 = e % 64, px = e / 64;
    const u32 v = fb[(size_t)px * 64 + c2];
    const int lab = ll[px];
    atomicAdd(&acc[lab * 129 + 2 * c2],     __uint_as_float(v << 16));
    atomicAdd(&acc[lab * 129 + 2 * c2 + 1], __uint_as_float(v & 0xffff0000u));
  }
  __syncthreads();
  for (int e = t; e < NCLS * 128; e += 256)
    atomicAdd(&sums_f[b * NCLS * 128 + e], acc[(e / 128) * 129 + (e % 128)]);
}

// ===========================================================================
// K6: gates.  One block per batch, reads tiny sums[b][41][128].
// ===========================================================================
__global__ __launch_bounds__(256) void k_gates(const float* __restrict__ sums,
                                               const int* __restrict__ counts,
                                               const float* __restrict__ w1,
                                               const float* __restrict__ w2,
                                               float* __restrict__ gates) {
  const int b = blockIdx.x;
  __shared__ float att[128];
  __shared__ float hid[8];
  const int t = threadIdx.x;
  if (t < 128) {
    float s1 = 0.f, s2 = 0.f;
    for (int lb = 0; lb < NCLS; ++lb) {
      const float cnt = (float)counts[b * NCLS + lb];
      const float m = sums[(size_t)b * NCLS * 128 + lb * 128 + t] / fmaxf(cnt, 1.f);
      s1 += m; s2 += m * m;
    }
    att[t] = s1 / fmaxf(sqrtf(s2), 1e-12f);
  }
  __syncthreads();
  if (t < 8) {
    float h = 0.f;
    for (int c = 0; c < 128; ++c) h += att[c] * w1[t * 128 + c];
    hid[t] = fmaxf(h, 0.f);
  }
  __syncthreads();
  if (t < 128) {
    float o = 0.f;
    for (int j = 0; j < 8; ++j) o += hid[j] * w2[t * 8 + j];
    gates[b * 128 + t] = 1.f / (1.f + expf(-o));
  }
}

// ===========================================================================
// K7: out(NCHW f32) = fuse(NHWC bf16)*gate_f + d(NCHW)*gate_d
//     Block = (b,y); LDS transpose of fuse row back to channel-major.
// ===========================================================================
__global__ __launch_bounds__(256) void k_out(const u16* __restrict__ fuse,
                                             const float* __restrict__ d,
                                             const float* __restrict__ gates,
                                             float* __restrict__ out) {
  const int y = blockIdx.x % 224, b = blockIdx.x / 224;
  __shared__ float flds[224 * 33];
  __shared__ float gf[128], gd[128];
  const int t = threadIdx.x;
  if (t < 128) gd[t] = gates[b * 128 + t];
  else         gf[t - 128] = gates[512 + b * 128 + (t - 128)];
  const u32* frow = (const u32*)fuse + ((size_t)b * 224 + y) * 224 * 64;
  const float* db = d + (size_t)b * 128 * 50176 + y * 224;
  float* ob = out + (size_t)b * 128 * 50176 + y * 224;
  for (int c0 = 0; c0 < 128; c0 += 32) {
    __syncthreads();
    for (int e = t; e < 224 * 16; e += 256) {
      const int px = e / 16, q = e % 16;
      const u32 v = frow[(size_t)px * 64 + (c0 >> 1) + q];
      flds[px * 33 + 2 * q]     = __uint_as_float(v << 16);
      flds[px * 33 + 2 * q + 1] = __uint_as_float(v & 0xffff0000u);
    }
    __syncthreads();
    for (int e = t; e < 32 * 224; e += 256) {
      const int cc = e / 224, x = e % 224, c = c0 + cc;
      ob[(size_t)c * 50176 + x] = flds[x * 33 + cc] * gf[c] + db[(size_t)c * 50176 + x] * gd[c];
    }
  }
}

// ===========================================================================
extern "C" void kernel_launch(void* const* d_in, const int* in_sizes, int n_in,
                              void* d_out, int out_size, void* d_ws, size_t ws_size,
                              hipStream_t stream) {
  const float* r     = (const float*)d_in[0];
  const float* d     = (const float*)d_in[1];
  const int*   label = (const int*)d_in[2];
  const float* wf    = (const float*)d_in[3];
  const float* w1d   = (const float*)d_in[4];
  const float* w2d   = (const float*)d_in[5];
  const float* w1f   = (const float*)d_in[6];
  const float* w2f   = (const float*)d_in[7];
  float* out = (float*)d_out;

  char* ws = (char*)d_ws;
  size_t off = 0;
  auto carve = [&](size_t bytes) -> char* {
    char* p = ws + off;
    off = (off + bytes + 511) & ~(size_t)511;
    return p;
  };
  u16* X       = (u16*)carve((size_t)4 * 226 * 226 * 256 * 2 + 65536);  // slice-major + OOB pad
  u16* Wt      = (u16*)carve((size_t)9 * 128 * 256 * 2);
  u16* fuseb   = (u16*)carve((size_t)4 * 224 * 224 * 128 * 2);
  u8*  labs    = (u8*) carve((size_t)4 * 224 * 224);
  int* counts  = (int*)carve(4 * NCLS * sizeof(int));
  float* sumsd = (float*)carve((size_t)4 * NCLS * 128 * 4);
  float* sumsf = (float*)carve((size_t)4 * NCLS * 128 * 4);
  float* gates = (float*)carve(1024 * sizeof(float));

  hipMemsetAsync(counts, 0, 4 * NCLS * sizeof(int), stream);
  hipMemsetAsync(sumsd, 0, (size_t)4 * NCLS * 128 * 4, stream);
  hipMemsetAsync(sumsf, 0, (size_t)4 * NCLS * 128 * 4, stream);
  k_wprep <<<(9 * 128 * 256 + 255) / 256, 256, 0, stream>>>(wf, Wt);
  k_labels<<<4 * 224, 256, 0, stream>>>(label, labs, counts);
  k_prep  <<<4 * 226 * 2, 256, 0, stream>>>(r, d, labs, X, sumsd);
  k_conv  <<<1792, 256, 0, stream>>>(X, Wt, fuseb);
  k_segf  <<<4 * 224, 256, 0, stream>>>(fuseb, labs, sumsf);
  k_gates <<<4, 256, 0, stream>>>(sumsd, counts, w1d, w2d, gates);        // gates[0..511]   = d-module
  k_gates <<<4, 256, 0, stream>>>(sumsf, counts, w1f, w2f, gates + 512);  // gates[512..1023]= fuse-module
  k_out   <<<4 * 224, 256, 0, stream>>>(fuseb, d, gates, out);
}

// Round 5
// 720.520 us; speedup vs baseline: 1.0921x; 1.0002x over previous
//
#include <hip/hip_runtime.h>
#include <hip/hip_bf16.h>
#include <cstdint>
#include <cstddef>

typedef unsigned short u16;
typedef unsigned int   u32;
typedef unsigned char  u8;

#define NCLS 41

typedef short s16x8 __attribute__((ext_vector_type(8)));
typedef float f32x4 __attribute__((ext_vector_type(4)));

__device__ __forceinline__ u16 f2bf(float f) {          // RNE float->bf16
  u32 u = __float_as_uint(f);
  u += 0x7fffu + ((u >> 16) & 1u);
  return (u16)(u >> 16);
}

// ---- async global->LDS (16B/lane, wave-uniform LDS base) ------------------
#if __has_builtin(__builtin_amdgcn_global_load_lds)
#define HAVE_GLL 1
typedef const __attribute__((address_space(1))) u32* gas1p;
typedef __attribute__((address_space(3))) u32* las3p;
__device__ __forceinline__ void gll16(const void* g, void* l) {
  __builtin_amdgcn_global_load_lds((gas1p)g, (las3p)l, 16, 0, 0);
}
#else
#define HAVE_GLL 0
#endif

// ===========================================================================
// K_w: w_fuse [128oc][256ic][3][3] f32  ->  Wt [9tap][128oc][256ic] bf16
// ===========================================================================
__global__ void k_wprep(const float* __restrict__ wf, u16* __restrict__ Wt) {
  const int e = blockIdx.x * 256 + threadIdx.x;
  if (e >= 9 * 128 * 256) return;
  const int tap = e / (128 * 256);
  const int oc  = (e / 256) % 128;
  const int ic  = e % 256;
  Wt[e] = f2bf(wf[((size_t)oc * 256 + ic) * 9 + tap]);
}

// ===========================================================================
// K2: labels_ds (::4,::4) -> u8 [4][224][224]; histogram -> counts[4*41]
// ===========================================================================
__global__ void k_labels(const int* __restrict__ label, u8* __restrict__ labs,
                         int* __restrict__ counts) {
  const int i = blockIdx.x % 224, b = blockIdx.x / 224;
  __shared__ int hist[NCLS];
  const int t = threadIdx.x;
  if (t < NCLS) hist[t] = 0;
  __syncthreads();
  if (t < 224) {
    const int v = label[((size_t)b * 896 + 4 * i) * 896 + 4 * t];
    labs[((size_t)b * 224 + i) * 224 + t] = (u8)v;
    atomicAdd(&hist[v], 1);
  }
  __syncthreads();
  if (t < NCLS) atomicAdd(&counts[b * NCLS + t], hist[t]);
}

// ===========================================================================
// K1: build X = padded bf16, SLICE-MAJOR layout:
//     X[b][yp][s][px][32ch], s=0..7: s<4 -> a=r+d (ch 32s..), s>=4 -> m=r*sig(d).
//     Block = (b, yp, s4): ONE 32-ch slice per block (grid 3616, 2x TLP vs
//     R4).  Thread = pixel: issues all 64 loads (32 r + 32 d) in ONE burst
//     (16 KB outstanding/wave, ~4x MLP of the 16-ch chunked version), then
//     packs and stores the FULL 64-B px block of both the a- and m-slice as
//     4+4 consecutive uint4 -> wave stores are contiguous 4 KB runs.
//     d-segsum fused as LDS atomics acc[lab*33+c] (5.4 KB), flushed once.
// ===========================================================================
__global__ __launch_bounds__(256) void k_prep(const float* __restrict__ r,
                                              const float* __restrict__ d,
                                              const u8* __restrict__ labs,
                                              u16* __restrict__ X,
                                              float* __restrict__ sums_d) {
  const int t  = threadIdx.x;
  const int s4 = blockIdx.x & 3;
  const int yp = (blockIdx.x >> 2) % 226;
  const int b  = blockIdx.x / (226 * 4);

  if (yp == 0 || yp == 225) {                       // y-halo rows: zero 2 slices
    uint4* za = (uint4*)(X + (((size_t)(b * 226 + yp) * 8 + s4)     * 226) * 32);
    uint4* zm = (uint4*)(X + (((size_t)(b * 226 + yp) * 8 + s4 + 4) * 226) * 32);
    for (int e = t; e < 226 * 4; e += 256) {
      za[e] = uint4{0u, 0u, 0u, 0u};
      zm[e] = uint4{0u, 0u, 0u, 0u};
    }
    return;
  }
  const int y = yp - 1;

  __shared__ float acc[NCLS * 33];                  // seg-sum of d (32 ch + pad)
  for (int e = t; e < NCLS * 33; e += 256) acc[e] = 0.f;
  __syncthreads();

  if (t < 224) {
    const int x = t;
    const int lab = (int)labs[((size_t)b * 224 + y) * 224 + x];
    const float* rb = r + ((size_t)b * 128 + s4 * 32) * 50176 + y * 224 + x;
    const float* db = d + ((size_t)b * 128 + s4 * 32) * 50176 + y * 224 + x;
    float rv[32], dv[32];
#pragma unroll
    for (int j = 0; j < 32; ++j) rv[j] = rb[(size_t)j * 50176];
#pragma unroll
    for (int j = 0; j < 32; ++j) dv[j] = db[(size_t)j * 50176];
#pragma unroll
    for (int j = 0; j < 32; ++j)
      atomicAdd(&acc[lab * 33 + j], dv[j]);         // distinct ch per j; lanes
                                                    // collide only on equal lab
    u32 pa[16], pm[16];
#pragma unroll
    for (int j = 0; j < 16; ++j) {
      const float r0 = rv[2 * j], r1 = rv[2 * j + 1];
      const float d0 = dv[2 * j], d1 = dv[2 * j + 1];
      pa[j] = (u32)f2bf(r0 + d0) | ((u32)f2bf(r1 + d1) << 16);
      pm[j] = (u32)f2bf(r0 / (1.f + __expf(-d0)))
            | ((u32)f2bf(r1 / (1.f + __expf(-d1))) << 16);
    }
    u32* Xa = (u32*)(X + ((((size_t)(b * 226 + yp) * 8 + s4)     * 226) + (x + 1)) * 32);
    u32* Xm = (u32*)(X + ((((size_t)(b * 226 + yp) * 8 + s4 + 4) * 226) + (x + 1)) * 32);
    *(uint4*)(Xa)      = uint4{pa[0],  pa[1],  pa[2],  pa[3]};
    *(uint4*)(Xa + 4)  = uint4{pa[4],  pa[5],  pa[6],  pa[7]};
    *(uint4*)(Xa + 8)  = uint4{pa[8],  pa[9],  pa[10], pa[11]};
    *(uint4*)(Xa + 12) = uint4{pa[12], pa[13], pa[14], pa[15]};
    *(uint4*)(Xm)      = uint4{pm[0],  pm[1],  pm[2],  pm[3]};
    *(uint4*)(Xm + 4)  = uint4{pm[4],  pm[5],  pm[6],  pm[7]};
    *(uint4*)(Xm + 8)  = uint4{pm[8],  pm[9],  pm[10], pm[11]};
    *(uint4*)(Xm + 12) = uint4{pm[12], pm[13], pm[14], pm[15]};
  } else if (t < 240) {                             // x-halos: px 0 and 225
    const int idx = t - 224;                        // 2 slices x 2 px x 4 chunks
    const int chunk = idx & 3, pxsel = (idx >> 2) & 1, sl = (idx >> 3) & 1;
    const int s = s4 + sl * 4;
    const int px = pxsel * 225;
    uint4* p = (uint4*)(X + ((((size_t)(b * 226 + yp) * 8 + s) * 226) + px) * 32) + chunk;
    *p = uint4{0u, 0u, 0u, 0u};
  }
  __syncthreads();                                  // acc complete
  for (int e = t; e < NCLS * 32; e += 256)
    atomicAdd(&sums_d[(size_t)b * NCLS * 128 + (e >> 5) * 128 + s4 * 32 + (e & 31)],
              acc[(e >> 5) * 33 + (e & 31)]);
}

// ===========================================================================
// K4: conv3x3 as implicit GEMM, bf16 MFMA 16x16x32.  dx-SHARED phases:
//     phase = (dy, s): stage ONE 130-pos A panel (row y+dy, slice s) + the
//     3 dx B-panels, then compute all 3 dx from LDS (A read offset +dx*64B).
//     48 MFMA/wave between barriers, 48 barriers, A-fetch cut 3x.
//     Single-buffered (R3 explicit dbuf regressed).  XCD-band swizzle on L%8.
// ===========================================================================
__global__ __launch_bounds__(256) void k_conv(const u16* __restrict__ X,
                                              const u16* __restrict__ Wt,
                                              u16* __restrict__ fuse) {
  __shared__ u16 Alds[132 * 32];         // 130 pos used (+2 pad)
  __shared__ u16 Blds[3][128 * 32];
  const int t = threadIdx.x;
  const int w = t >> 6, l = t & 63;
  const int lrow = l & 15, lq = l >> 4;
  const int wm = (w & 1) * 64, wn = (w >> 1) * 64;

  const int L   = blockIdx.x;        // 1792 blocks
  const int xcd = L & 7;             // heuristic: linear id % 8 = XCD
  const int i   = L >> 3;            // 0..223
  const int b   = i / 56;
  const int rem = i % 56;            // 28 y x 2 xtiles
  const int y   = xcd * 28 + (rem >> 1);
  const int x0  = (rem & 1) * 128;

  f32x4 acc[4][4] = {};

  const int posA = t >> 2;          // staging: lane covers (pos/oc, 16B chunk)
  const int koff = (t & 3) * 8;     // u16 units
  const size_t browb = (size_t)(b * 226 + y) * 8;   // slice-major row base
  char* ldsA0 = (char*)Alds + (w * 64) * 16;        // wave-uniform LDS bases

  for (int dy = 0; dy < 3; ++dy) {
    for (int s = 0; s < 8; ++s) {
      const u16* Abase = X + ((browb + dy * 8 + s) * 226 + x0) * 32;
      // ---- stage A: 128 pos via 2 gll rounds + 2-pos tail (reg->LDS) ----
#if HAVE_GLL
      gll16(Abase + posA * 32 + koff,        ldsA0);
      gll16(Abase + (64 + posA) * 32 + koff, ldsA0 + 4096);
#else
      *(uint4*)((char*)Alds + t * 16)        = *(const uint4*)(Abase + posA * 32 + koff);
      *(uint4*)((char*)Alds + 4096 + t * 16) = *(const uint4*)(Abase + (64 + posA) * 32 + koff);
#endif
      if (t < 8)   // pos 128..129 (x0=128: in-bounds pad garbage, epilogue-masked)
        *(uint4*)((char*)Alds + 8192 + t * 16) = *(const uint4*)(Abase + 128 * 32 + t * 8);
      // ---- stage B: 3 taps (dy,dx) x 2 rounds --------------------------
#pragma unroll
      for (int dx = 0; dx < 3; ++dx) {
        const u16* Bbase = Wt + (size_t)(dy * 3 + dx) * (128 * 256) + s * 32;
        char* ldsB0 = (char*)Blds[dx] + (w * 64) * 16;
#if HAVE_GLL
        gll16(Bbase + posA * 256 + koff,        ldsB0);
        gll16(Bbase + (64 + posA) * 256 + koff, ldsB0 + 4096);
#else
        *(uint4*)((char*)Blds[dx] + t * 16)        = *(const uint4*)(Bbase + posA * 256 + koff);
        *(uint4*)((char*)Blds[dx] + 4096 + t * 16) = *(const uint4*)(Bbase + (64 + posA) * 256 + koff);
#endif
      }
      __syncthreads();
      // ---- compute: 3 dx from the shared A panel -----------------------
#pragma unroll
      for (int dx = 0; dx < 3; ++dx) {
        s16x8 af[4], bfr[4];
#pragma unroll
        for (int mi = 0; mi < 4; ++mi)
          af[mi] = *(const s16x8*)((const char*)Alds + (wm + mi * 16 + lrow + dx) * 64 + lq * 16);
#pragma unroll
        for (int ni = 0; ni < 4; ++ni)
          bfr[ni] = *(const s16x8*)((const char*)Blds[dx] + (wn + ni * 16 + lrow) * 64 + lq * 16);
#pragma unroll
        for (int mi = 0; mi < 4; ++mi)
#pragma unroll
          for (int ni = 0; ni < 4; ++ni)
            acc[mi][ni] = __builtin_amdgcn_mfma_f32_16x16x32_bf16(af[mi], bfr[ni], acc[mi][ni], 0, 0, 0);
      }
      __syncthreads();
    }
  }
  // epilogue: D row = pos (C/D layout row = lq*4+reg), col = oc (l&15)
#pragma unroll
  for (int mi = 0; mi < 4; ++mi) {
#pragma unroll
    for (int rr = 0; rr < 4; ++rr) {
      const int pos = wm + mi * 16 + lq * 4 + rr;
      const int x = x0 + pos;
      if (x < 224) {
        u16* dst = fuse + ((size_t)(b * 224 + y) * 224 + x) * 128;
#pragma unroll
        for (int ni = 0; ni < 4; ++ni) {
          const int oc = wn + ni * 16 + lrow;
          dst[oc] = f2bf(acc[mi][ni][rr]);
        }
      }
    }
  }
}

// ===========================================================================
// K5: segment-sum of fuse (NHWC bf16) -> global atomics into sums_f.
//     Block = (b, y): one row, 224 px x 64 u32.  Lanes walk channels of one
//     pixel -> all lanes share the label, distinct channels (no same-addr
//     serialization).
// ===========================================================================
__global__ __launch_bounds__(256) void k_segf(const u16* __restrict__ fuse,
                                              const u8* __restrict__ labs,
                                              float* __restrict__ sums_f) {
  const int y = blockIdx.x % 224, b = blockIdx.x / 224;
  __shared__ float acc[NCLS * 129];
  __shared__ u8 ll[224];
  const int t = threadIdx.x;
  for (int e = t; e < NCLS * 129; e += 256) acc[e] = 0.f;
  if (t < 224) ll[t] = labs[((size_t)b * 224 + y) * 224 + t];
  __syncthreads();
  const u32* fb = (const u32*)(fuse + ((size_t)b * 224 + y) * 224 * 128);
  for (int e = t; e < 224 * 64; e += 256) {
    const int c2 = e % 64, px = e / 64;
    const u32 v = fb[(size_t)px * 64 + c2];
    const int lab = ll[px];
    atomicAdd(&acc[lab * 129 + 2 * c2],     __uint_as_float(v << 16));
    atomicAdd(&acc[lab * 129 + 2 * c2 + 1], __uint_as_float(v & 0xffff0000u));
  }
  __syncthreads();
  for (int e = t; e < NCLS * 128; e += 256)
    atomicAdd(&sums_f[b * NCLS * 128 + e], acc[(e / 128) * 129 + (e % 128)]);
}

// ===========================================================================
// K6: gates.  One block per batch, reads tiny sums[b][41][128].
// ===========================================================================
__global__ __launch_bounds__(256) void k_gates(const float* __restrict__ sums,
                                               const int* __restrict__ counts,
                                               const float* __restrict__ w1,
                                               const float* __restrict__ w2,
                                               float* __restrict__ gates) {
  const int b = blockIdx.x;
  __shared__ float att[128];
  __shared__ float hid[8];
  const int t = threadIdx.x;
  if (t < 128) {
    float s1 = 0.f, s2 = 0.f;
    for (int lb = 0; lb < NCLS; ++lb) {
      const float cnt = (float)counts[b * NCLS + lb];
      const float m = sums[(size_t)b * NCLS * 128 + lb * 128 + t] / fmaxf(cnt, 1.f);
      s1 += m; s2 += m * m;
    }
    att[t] = s1 / fmaxf(sqrtf(s2), 1e-12f);
  }
  __syncthreads();
  if (t < 8) {
    float h = 0.f;
    for (int c = 0; c < 128; ++c) h += att[c] * w1[t * 128 + c];
    hid[t] = fmaxf(h, 0.f);
  }
  __syncthreads();
  if (t < 128) {
    float o = 0.f;
    for (int j = 0; j < 8; ++j) o += hid[j] * w2[t * 8 + j];
    gates[b * 128 + t] = 1.f / (1.f + expf(-o));
  }
}

// ===========================================================================
// K7: out(NCHW f32) = fuse(NHWC bf16)*gate_f + d(NCHW)*gate_d
//     Block = (b,y); LDS transpose of fuse row back to channel-major.
// ===========================================================================
__global__ __launch_bounds__(256) void k_out(const u16* __restrict__ fuse,
                                             const float* __restrict__ d,
                                             const float* __restrict__ gates,
                                             float* __restrict__ out) {
  const int y = blockIdx.x % 224, b = blockIdx.x / 224;
  __shared__ float flds[224 * 33];
  __shared__ float gf[128], gd[128];
  const int t = threadIdx.x;
  if (t < 128) gd[t] = gates[b * 128 + t];
  else         gf[t - 128] = gates[512 + b * 128 + (t - 128)];
  const u32* frow = (const u32*)fuse + ((size_t)b * 224 + y) * 224 * 64;
  const float* db = d + (size_t)b * 128 * 50176 + y * 224;
  float* ob = out + (size_t)b * 128 * 50176 + y * 224;
  for (int c0 = 0; c0 < 128; c0 += 32) {
    __syncthreads();
    for (int e = t; e < 224 * 16; e += 256) {
      const int px = e / 16, q = e % 16;
      const u32 v = frow[(size_t)px * 64 + (c0 >> 1) + q];
      flds[px * 33 + 2 * q]     = __uint_as_float(v << 16);
      flds[px * 33 + 2 * q + 1] = __uint_as_float(v & 0xffff0000u);
    }
    __syncthreads();
    for (int e = t; e < 32 * 224; e += 256) {
      const int cc = e / 224, x = e % 224, c = c0 + cc;
      ob[(size_t)c * 50176 + x] = flds[x * 33 + cc] * gf[c] + db[(size_t)c * 50176 + x] * gd[c];
    }
  }
}

// ===========================================================================
extern "C" void kernel_launch(void* const* d_in, const int* in_sizes, int n_in,
                              void* d_out, int out_size, void* d_ws, size_t ws_size,
                              hipStream_t stream) {
  const float* r     = (const float*)d_in[0];
  const float* d     = (const float*)d_in[1];
  const int*   label = (const int*)d_in[2];
  const float* wf    = (const float*)d_in[3];
  const float* w1d   = (const float*)d_in[4];
  const float* w2d   = (const float*)d_in[5];
  const float* w1f   = (const float*)d_in[6];
  const float* w2f   = (const float*)d_in[7];
  float* out = (float*)d_out;

  char* ws = (char*)d_ws;
  size_t off = 0;
  auto carve = [&](size_t bytes) -> char* {
    char* p = ws + off;
    off = (off + bytes + 511) & ~(size_t)511;
    return p;
  };
  u16* X       = (u16*)carve((size_t)4 * 226 * 226 * 256 * 2 + 65536);  // slice-major + OOB pad
  u16* Wt      = (u16*)carve((size_t)9 * 128 * 256 * 2);
  u16* fuseb   = (u16*)carve((size_t)4 * 224 * 224 * 128 * 2);
  u8*  labs    = (u8*) carve((size_t)4 * 224 * 224);
  int* counts  = (int*)carve(4 * NCLS * sizeof(int));
  float* sumsd = (float*)carve((size_t)4 * NCLS * 128 * 4);
  float* sumsf = (float*)carve((size_t)4 * NCLS * 128 * 4);
  float* gates = (float*)carve(1024 * sizeof(float));

  hipMemsetAsync(counts, 0, 4 * NCLS * sizeof(int), stream);
  hipMemsetAsync(sumsd, 0, (size_t)4 * NCLS * 128 * 4, stream);
  hipMemsetAsync(sumsf, 0, (size_t)4 * NCLS * 128 * 4, stream);
  k_wprep <<<(9 * 128 * 256 + 255) / 256, 256, 0, stream>>>(wf, Wt);
  k_labels<<<4 * 224, 256, 0, stream>>>(label, labs, counts);
  k_prep  <<<4 * 226 * 4, 256, 0, stream>>>(r, d, labs, X, sumsd);
  k_conv  <<<1792, 256, 0, stream>>>(X, Wt, fuseb);
  k_segf  <<<4 * 224, 256, 0, stream>>>(fuseb, labs, sumsf);
  k_gates <<<4, 256, 0, stream>>>(sumsd, counts, w1d, w2d, gates);        // gates[0..511]   = d-module
  k_gates <<<4, 256, 0, stream>>>(sumsf, counts, w1f, w2f, gates + 512);  // gates[512..1023]= fuse-module
  k_out   <<<4 * 224, 256, 0, stream>>>(fuseb, d, gates, out);
}